// Round 11
// baseline (477.044 us; speedup 1.0000x reference)
//
#include <hip/hip_runtime.h>

#define N_NODES 100000
#define N_EDGES 1600000
#define IN_DIM  128
#define HID     64
#define MLP_HID 256
#define OUT_DIM 128

#define CB_SHIFT 9
#define CB_SIZE  512
#define NB_C     196   // ceil(100000/512)
#define ECAP     9216  // fixed bucket window capacity (mean 8192 + ~11 sigma)

typedef __attribute__((ext_vector_type(4))) float fx4;
typedef __attribute__((ext_vector_type(8))) short bf16x8;
typedef __attribute__((ext_vector_type(4))) unsigned short u16x4;
typedef __attribute__((ext_vector_type(8))) unsigned short u16x8;
typedef unsigned short u16;

// ---------------- bf16 hi/lo split helpers (HW cvt) ----------------

__device__ __forceinline__ u16 f2b(float x) {
  __bf16 h = (__bf16)x;                     // RNE hardware convert
  return __builtin_bit_cast(u16, h);
}

__device__ __forceinline__ void bsplit(float x, u16& hb, u16& lb) {
  hb = f2b(x);
  float hf = __uint_as_float((unsigned)hb << 16);   // exact reconstruction
  lb = f2b(x - hf);                                  // exact residual, RNE
}

// ---------------- graph build: bucketed counting sort (fixed-capacity windows) -----------

__global__ void k_init_cur(int* __restrict__ ccur) {
  int i = threadIdx.x;
  if (i < NB_C) ccur[i] = i * ECAP;
}

// P1: partition edges into fixed coarse-bucket windows, packed u32 = src<<9 | dst_low9
__global__ __launch_bounds__(256)
void k_partition(const int* __restrict__ src, const int* __restrict__ dst,
                 int* __restrict__ ccur, unsigned* __restrict__ ebuf) {
  __shared__ int h[NB_C];
  __shared__ int bwin[NB_C];
  for (int i = threadIdx.x; i < NB_C; i += 256) h[i] = 0;
  __syncthreads();
  int base = blockIdx.x * 8192;
  int d[32];
  #pragma unroll
  for (int k = 0; k < 32; k++) {
    int i = base + k * 256 + threadIdx.x;
    d[k] = (i < N_EDGES) ? dst[i] : -1;
    if (d[k] >= 0) atomicAdd(&h[d[k] >> CB_SHIFT], 1);
  }
  __syncthreads();
  for (int i = threadIdx.x; i < NB_C; i += 256) {
    int c = h[i];
    bwin[i] = c ? atomicAdd(&ccur[i], c) : 0;
  }
  __syncthreads();
  for (int i = threadIdx.x; i < NB_C; i += 256) h[i] = 0;  // reuse as local cursor
  __syncthreads();
  #pragma unroll
  for (int k = 0; k < 32; k++) {
    if (d[k] >= 0) {
      int i = base + k * 256 + threadIdx.x;
      int b = d[k] >> CB_SHIFT;
      int loc = atomicAdd(&h[b], 1);
      ebuf[bwin[b] + loc] = ((unsigned)src[i] << CB_SHIFT) | (unsigned)(d[k] & (CB_SIZE - 1));
    }
  }
}

// tiny scan of bucket sizes -> csr base per bucket
__global__ void k_scan_sizes(const int* __restrict__ ccur, int* __restrict__ cbase) {
  if (threadIdx.x == 0 && blockIdx.x == 0) {
    int run = 0;
    #pragma unroll 1
    for (int b = 0; b < NB_C; b++) { cbase[b] = run; run += ccur[b] - b * ECAP; }
    cbase[NB_C] = run;
  }
}

// merged: per-bucket hist -> scan -> offsets + dinv -> scatter (LDS cursors)
__global__ __launch_bounds__(256)
void k_bucket_csr(const unsigned* __restrict__ ebuf, const int* __restrict__ ccur,
                  const int* __restrict__ cbase, int* __restrict__ offsets,
                  float* __restrict__ dinv, int* __restrict__ csr_src) {
  __shared__ int h[CB_SIZE];
  __shared__ int ts[256];
  int b = blockIdx.x, t = threadIdx.x;
  for (int i = t; i < CB_SIZE; i += 256) h[i] = 0;
  __syncthreads();
  int e0 = b * ECAP, e1 = ccur[b];
  for (int e = e0 + t; e < e1; e += 256)
    atomicAdd(&h[ebuf[e] & (CB_SIZE - 1)], 1);
  __syncthreads();
  int n0 = b * CB_SIZE;
  int c0 = h[2 * t], c1 = h[2 * t + 1];
  if (n0 + 2 * t     < N_NODES) dinv[n0 + 2 * t]     = rsqrtf((float)(c0 + 1));
  if (n0 + 2 * t + 1 < N_NODES) dinv[n0 + 2 * t + 1] = rsqrtf((float)(c1 + 1));
  int my = c0 + c1;
  ts[t] = my;
  __syncthreads();
  int v = my;
  for (int off = 1; off < 256; off <<= 1) {
    int y = (t >= off) ? ts[t - off] : 0;
    __syncthreads();
    v += y;
    ts[t] = v;
    __syncthreads();
  }
  int excl = cbase[b] + v - my;
  if (n0 + 2 * t     < N_NODES) offsets[n0 + 2 * t]     = excl;
  if (n0 + 2 * t + 1 < N_NODES) offsets[n0 + 2 * t + 1] = excl + c0;
  if (b == NB_C - 1 && t == 0) offsets[N_NODES] = cbase[NB_C];
  // convert h into global cursors
  h[2 * t]     = excl;
  h[2 * t + 1] = excl + c0;
  __syncthreads();
  for (int e = e0 + t; e < e1; e += 256) {
    unsigned p = ebuf[e];
    int pos = atomicAdd(&h[p & (CB_SIZE - 1)], 1);
    csr_src[pos] = (int)(p >> CB_SHIFT);
  }
}

// ---------------- weight pre-pack (all 5 matrices, one kernel) ----------------
// Fragment for (ntile, ks): lane l holds B[k = ks*32 + (l>>4)*8 + j][col = ntile*16 + (l&15)]

__device__ __forceinline__ void pack_one(const float* __restrict__ W, int K, int N, int t,
                                         u16* __restrict__ hi, u16* __restrict__ lo) {
  int k = t / N, n = t % N;
  u16 hb, lb;
  bsplit(W[t], hb, lb);
  int nt = n >> 4, col = n & 15;
  int ks = k >> 5, kr = k & 31;
  int lane = (kr >> 3) * 16 + col;
  int j = kr & 7;
  int ksteps = K >> 5;
  size_t idx = (((size_t)(nt * ksteps + ks)) * 64 + lane) * 8 + j;
  hi[idx] = hb;
  lo[idx] = lb;
}

__global__ __launch_bounds__(256)
void k_pack_all(const float* __restrict__ W1, const float* __restrict__ W2,
                const float* __restrict__ Wf1, const float* __restrict__ Wf2,
                const float* __restrict__ Wf3,
                u16* pw1h, u16* pw1l, u16* pw2h, u16* pw2l,
                u16* p1h, u16* p1l, u16* p2h, u16* p2l, u16* p3h, u16* p3l) {
  int tid = blockIdx.x * 256 + threadIdx.x;
  if (tid < 8192)        pack_one(W1,  IN_DIM,  HID,     tid,          pw1h, pw1l);
  else if (tid < 12288)  pack_one(W2,  HID,     HID,     tid - 8192,   pw2h, pw2l);
  else if (tid < 28672)  pack_one(Wf1, HID,     MLP_HID, tid - 12288,  p1h,  p1l);
  else if (tid < 94208)  pack_one(Wf2, MLP_HID, MLP_HID, tid - 28672,  p2h,  p2l);
  else if (tid < 126976) pack_one(Wf3, MLP_HID, OUT_DIM, tid - 94208,  p3h,  p3l);
}

// ---------------- conv linear via split-bf16 MFMA: out[n] = (X[n] @ W) * dinv[n] -------------
// 512 threads = 8 waves, 64 nodes/block. wave w: m-pair = w>>2, n-tile = w&3.

template<int K, bool SPLIT>
__global__ __launch_bounds__(512, 4)
void k_conv(const float* __restrict__ Xf, const u16* __restrict__ Xh, const u16* __restrict__ Xl,
            const u16* __restrict__ wh, const u16* __restrict__ wl,
            const float* __restrict__ dinv, float* __restrict__ out) {
  constexpr int STRIDE = K + 8;
  constexpr int KS = K / 32;
  __shared__ u16 s_h[64][STRIDE];
  __shared__ u16 s_l[64][STRIDE];
  const int t = threadIdx.x;
  const int base = blockIdx.x * 64;

  if constexpr (!SPLIT) {
    const int tot4 = 64 * K / 4;
    for (int i = t; i < tot4; i += 512) {
      int f = i * 4;
      int r = f / K, c = f % K;
      int row = base + r;
      if (row >= N_NODES) row = N_NODES - 1;
      float4 v = *(const float4*)(Xf + (size_t)row * K + c);
      u16x4 h4, l4;
      u16 hb, lb;
      bsplit(v.x, hb, lb); h4[0] = hb; l4[0] = lb;
      bsplit(v.y, hb, lb); h4[1] = hb; l4[1] = lb;
      bsplit(v.z, hb, lb); h4[2] = hb; l4[2] = lb;
      bsplit(v.w, hb, lb); h4[3] = hb; l4[3] = lb;
      *(u16x4*)&s_h[r][c] = h4;
      *(u16x4*)&s_l[r][c] = l4;
    }
  } else {
    const int tot8 = 64 * K / 8;
    for (int i = t; i < tot8; i += 512) {
      int r = i / (K / 8), c = (i % (K / 8)) * 8;
      int row = base + r;
      if (row >= N_NODES) row = N_NODES - 1;
      *(u16x8*)&s_h[r][c] = *(const u16x8*)(Xh + (size_t)row * K + c);
      *(u16x8*)&s_l[r][c] = *(const u16x8*)(Xl + (size_t)row * K + c);
    }
  }
  __syncthreads();

  const int w = t >> 6, lane = t & 63;
  const int mg = w >> 2;        // m-pair: m-tiles {2mg, 2mg+1}
  const int nt = w & 3;
  const int lr = lane & 15;
  const int lg = lane >> 4;
  const int kofs = lg * 8;
  const int dr = lg * 4;

  fx4 acc[2];
  #pragma unroll
  for (int m = 0; m < 2; m++) acc[m] = (fx4){0.f, 0.f, 0.f, 0.f};

  #pragma unroll
  for (int ks = 0; ks < KS; ks++) {
    size_t fi = ((size_t)(nt * KS + ks) * 64 + lane) * 8;
    bf16x8 bh = *(const bf16x8*)(wh + fi);
    bf16x8 bl = *(const bf16x8*)(wl + fi);
    #pragma unroll
    for (int m = 0; m < 2; m++) {
      int mrow = (mg * 2 + m) * 16 + lr;
      bf16x8 ah = *(const bf16x8*)&s_h[mrow][ks * 32 + kofs];
      bf16x8 al = *(const bf16x8*)&s_l[mrow][ks * 32 + kofs];
      acc[m] = __builtin_amdgcn_mfma_f32_16x16x32_bf16(al, bh, acc[m], 0, 0, 0);
      acc[m] = __builtin_amdgcn_mfma_f32_16x16x32_bf16(ah, bl, acc[m], 0, 0, 0);
      acc[m] = __builtin_amdgcn_mfma_f32_16x16x32_bf16(ah, bh, acc[m], 0, 0, 0);
    }
  }

  #pragma unroll
  for (int m = 0; m < 2; m++)
    #pragma unroll
    for (int r = 0; r < 4; r++) {
      int row = base + (mg * 2 + m) * 16 + dr + r;
      if (row < N_NODES)
        out[(size_t)row * 64 + nt * 16 + lr] = acc[m][r] * dinv[row];
    }
}

// ---------------- aggregation: writes pre-split bf16 hi/lo ----------------

__global__ __launch_bounds__(256)
void k_aggregate(const float* __restrict__ h, const int* __restrict__ offsets,
                 const int* __restrict__ csr_src, const float* __restrict__ dinv,
                 const float* __restrict__ bias,
                 u16* __restrict__ oh, u16* __restrict__ ol) {
  int lane = threadIdx.x & 63;
  int wid = (blockIdx.x * 256 + threadIdx.x) >> 6;
  int nw = (gridDim.x * 256) >> 6;
  float bv = bias[lane];
  for (int v = wid; v < N_NODES; v += nw) {
    int e0 = offsets[v], e1 = offsets[v + 1];
    float acc = h[(size_t)v * 64 + lane];   // self-loop (pre-scaled)
    int e = e0;
    for (; e + 8 <= e1; e += 8) {
      int s0 = __builtin_amdgcn_readfirstlane(csr_src[e + 0]);
      int s1 = __builtin_amdgcn_readfirstlane(csr_src[e + 1]);
      int s2 = __builtin_amdgcn_readfirstlane(csr_src[e + 2]);
      int s3 = __builtin_amdgcn_readfirstlane(csr_src[e + 3]);
      int s4 = __builtin_amdgcn_readfirstlane(csr_src[e + 4]);
      int s5 = __builtin_amdgcn_readfirstlane(csr_src[e + 5]);
      int s6 = __builtin_amdgcn_readfirstlane(csr_src[e + 6]);
      int s7 = __builtin_amdgcn_readfirstlane(csr_src[e + 7]);
      float a0 = h[(size_t)s0 * 64 + lane];
      float a1 = h[(size_t)s1 * 64 + lane];
      float a2 = h[(size_t)s2 * 64 + lane];
      float a3 = h[(size_t)s3 * 64 + lane];
      float a4 = h[(size_t)s4 * 64 + lane];
      float a5 = h[(size_t)s5 * 64 + lane];
      float a6 = h[(size_t)s6 * 64 + lane];
      float a7 = h[(size_t)s7 * 64 + lane];
      acc += ((a0 + a1) + (a2 + a3)) + ((a4 + a5) + (a6 + a7));
    }
    for (; e < e1; e++) {
      int s = __builtin_amdgcn_readfirstlane(csr_src[e]);
      acc += h[(size_t)s * 64 + lane];
    }
    float r = acc * dinv[v] + bv;
    r = r > 0.f ? r : 0.f;
    u16 hb, lb;
    bsplit(r, hb, lb);
    oh[(size_t)v * 64 + lane] = hb;
    ol[(size_t)v * 64 + lane] = lb;
  }
}

// ---------------- fused MLP via split-bf16 MFMA: 64 -> 256 -> 256 -> 128 ----------------
// R9 known-good form. blk0: node-block offset so the grid can be split into two
// half-launches (profiling visibility — every dispatch >46us becomes top-5-visible).

__global__ __launch_bounds__(512, 8)
void k_mlp(int blk0,
           const u16* __restrict__ Xh, const u16* __restrict__ Xl,
           const u16* __restrict__ w1h, const u16* __restrict__ w1l, const float* __restrict__ bb1,
           const u16* __restrict__ w2h, const u16* __restrict__ w2l, const float* __restrict__ bb2,
           const u16* __restrict__ w3h, const u16* __restrict__ w3l, const float* __restrict__ bb3,
           float* __restrict__ out) {
  __shared__ u16 s_h[32][264];
  __shared__ u16 s_l[32][264];
  const int t = threadIdx.x;
  const int w = t >> 6, lane = t & 63;
  const int base = (blk0 + blockIdx.x) * 32;
  const int lr = lane & 15;
  const int lg = lane >> 4;
  const int kofs = lg * 8;
  const int dr = lg * 4;

  fx4 acc[2][2];

  // ---- Layer 1: 64 -> 256 (ksteps=2), A direct from pre-split global ----
  #pragma unroll
  for (int m = 0; m < 2; m++)
    #pragma unroll
    for (int n = 0; n < 2; n++) acc[m][n] = (fx4){0.f, 0.f, 0.f, 0.f};
  #pragma unroll
  for (int ks = 0; ks < 2; ks++) {
    bf16x8 ah[2], al[2];
    #pragma unroll
    for (int m = 0; m < 2; m++) {
      int row = base + m * 16 + lr;
      ah[m] = *(const bf16x8*)(Xh + (size_t)row * 64 + ks * 32 + kofs);
      al[m] = *(const bf16x8*)(Xl + (size_t)row * 64 + ks * 32 + kofs);
    }
    #pragma unroll
    for (int n = 0; n < 2; n++) {
      size_t fi = ((size_t)((w * 2 + n) * 2 + ks) * 64 + lane) * 8;
      bf16x8 bh = *(const bf16x8*)(w1h + fi);
      bf16x8 bl = *(const bf16x8*)(w1l + fi);
      #pragma unroll
      for (int m = 0; m < 2; m++) {
        acc[m][n] = __builtin_amdgcn_mfma_f32_16x16x32_bf16(al[m], bh, acc[m][n], 0, 0, 0);
        acc[m][n] = __builtin_amdgcn_mfma_f32_16x16x32_bf16(ah[m], bl, acc[m][n], 0, 0, 0);
        acc[m][n] = __builtin_amdgcn_mfma_f32_16x16x32_bf16(ah[m], bh, acc[m][n], 0, 0, 0);
      }
    }
  }
  #pragma unroll
  for (int n = 0; n < 2; n++) {
    int nt = w * 2 + n;
    float bias = bb1[nt * 16 + lr];
    #pragma unroll
    for (int m = 0; m < 2; m++)
      #pragma unroll
      for (int r = 0; r < 4; r++) {
        float v = acc[m][n][r] + bias;
        v = v > 0.f ? v : 0.f;
        u16 hb, lb;
        bsplit(v, hb, lb);
        s_h[m * 16 + dr + r][nt * 16 + lr] = hb;
        s_l[m * 16 + dr + r][nt * 16 + lr] = lb;
      }
  }
  __syncthreads();

  // ---- Layer 2: 256 -> 256 (ksteps=8) ----
  #pragma unroll
  for (int m = 0; m < 2; m++)
    #pragma unroll
    for (int n = 0; n < 2; n++) acc[m][n] = (fx4){0.f, 0.f, 0.f, 0.f};
  #pragma unroll
  for (int ks = 0; ks < 8; ks++) {
    bf16x8 ah[2], al[2];
    #pragma unroll
    for (int m = 0; m < 2; m++) {
      ah[m] = *(const bf16x8*)&s_h[m * 16 + lr][ks * 32 + kofs];
      al[m] = *(const bf16x8*)&s_l[m * 16 + lr][ks * 32 + kofs];
    }
    #pragma unroll
    for (int n = 0; n < 2; n++) {
      size_t fi = ((size_t)((w * 2 + n) * 8 + ks) * 64 + lane) * 8;
      bf16x8 bh = *(const bf16x8*)(w2h + fi);
      bf16x8 bl = *(const bf16x8*)(w2l + fi);
      #pragma unroll
      for (int m = 0; m < 2; m++) {
        acc[m][n] = __builtin_amdgcn_mfma_f32_16x16x32_bf16(al[m], bh, acc[m][n], 0, 0, 0);
        acc[m][n] = __builtin_amdgcn_mfma_f32_16x16x32_bf16(ah[m], bl, acc[m][n], 0, 0, 0);
        acc[m][n] = __builtin_amdgcn_mfma_f32_16x16x32_bf16(ah[m], bh, acc[m][n], 0, 0, 0);
      }
    }
  }
  __syncthreads();
  #pragma unroll
  for (int n = 0; n < 2; n++) {
    int nt = w * 2 + n;
    float bias = bb2[nt * 16 + lr];
    #pragma unroll
    for (int m = 0; m < 2; m++)
      #pragma unroll
      for (int r = 0; r < 4; r++) {
        float v = acc[m][n][r] + bias;
        v = v > 0.f ? v : 0.f;
        u16 hb, lb;
        bsplit(v, hb, lb);
        s_h[m * 16 + dr + r][nt * 16 + lr] = hb;
        s_l[m * 16 + dr + r][nt * 16 + lr] = lb;
      }
  }
  __syncthreads();

  // ---- Layer 3: 256 -> 128 (ksteps=8); wave w -> n-tile w ----
  fx4 a3[2];
  #pragma unroll
  for (int m = 0; m < 2; m++) a3[m] = (fx4){0.f, 0.f, 0.f, 0.f};
  #pragma unroll
  for (int ks = 0; ks < 8; ks++) {
    size_t fi = ((size_t)(w * 8 + ks) * 64 + lane) * 8;
    bf16x8 bh = *(const bf16x8*)(w3h + fi);
    bf16x8 bl = *(const bf16x8*)(w3l + fi);
    #pragma unroll
    for (int m = 0; m < 2; m++) {
      bf16x8 ah = *(const bf16x8*)&s_h[m * 16 + lr][ks * 32 + kofs];
      bf16x8 al = *(const bf16x8*)&s_l[m * 16 + lr][ks * 32 + kofs];
      a3[m] = __builtin_amdgcn_mfma_f32_16x16x32_bf16(al, bh, a3[m], 0, 0, 0);
      a3[m] = __builtin_amdgcn_mfma_f32_16x16x32_bf16(ah, bl, a3[m], 0, 0, 0);
      a3[m] = __builtin_amdgcn_mfma_f32_16x16x32_bf16(ah, bh, a3[m], 0, 0, 0);
    }
  }
  {
    int col = w * 16 + lr;
    float bias = bb3[col];
    #pragma unroll
    for (int m = 0; m < 2; m++)
      #pragma unroll
      for (int r = 0; r < 4; r++) {
        int row = base + m * 16 + dr + r;
        float v = a3[m][r] + bias;
        out[(size_t)row * 128 + col] = v > 0.f ? v : 0.f;
      }
  }
}

// ---------------- launch ----------------

extern "C" void kernel_launch(void* const* d_in, const int* in_sizes, int n_in,
                              void* d_out, int out_size, void* d_ws, size_t ws_size,
                              hipStream_t stream) {
  const float* x   = (const float*)d_in[0];
  const int*   ei  = (const int*)d_in[1];
  const float* W1  = (const float*)d_in[2];
  const float* b1  = (const float*)d_in[3];
  const float* W2  = (const float*)d_in[4];
  const float* b2  = (const float*)d_in[5];
  const float* Wf1 = (const float*)d_in[6];
  const float* bf1 = (const float*)d_in[7];
  const float* Wf2 = (const float*)d_in[8];
  const float* bf2 = (const float*)d_in[9];
  const float* Wf3 = (const float*)d_in[10];
  const float* bf3 = (const float*)d_in[11];
  float* out = (float*)d_out;

  const int* src = ei;             // edge_index[0]
  const int* dst = ei + N_EDGES;   // edge_index[1]

  // workspace layout (16B-aligned chunks)
  int*      ccur    = (int*)d_ws;           // 256
  int*      cbase   = ccur + 256;           // 256 (NB_C+1 used)
  int*      offsets = cbase + 256;          // 100352+16
  int*      csr_src = offsets + 100368;     // E
  float*    dinv    = (float*)(csr_src + N_EDGES);
  float*    bufA    = dinv + 100352;                 // f32 conv output, N*64
  u16*      gh      = (u16*)(bufA + N_NODES * HID);  // pre-split aggregate out (hi)
  u16*      gl      = gh + 6400256;                  // (lo)
  u16*      p1h     = gl + 6400256;
  u16*      p1l     = p1h + HID * MLP_HID;
  u16*      p2h     = p1l + HID * MLP_HID;
  u16*      p2l     = p2h + MLP_HID * MLP_HID;
  u16*      p3h     = p2l + MLP_HID * MLP_HID;
  u16*      p3l     = p3h + MLP_HID * OUT_DIM;
  u16*      pw1h    = p3l + MLP_HID * OUT_DIM;
  u16*      pw1l    = pw1h + IN_DIM * HID;
  u16*      pw2h    = pw1l + IN_DIM * HID;
  u16*      pw2l    = pw2h + HID * HID;
  unsigned* ebuf    = (unsigned*)bufA;      // aliased (7.2MB of 25.6MB): dead before conv1

  k_init_cur  <<<1, 256, 0, stream>>>(ccur);
  k_partition <<<196, 256, 0, stream>>>(src, dst, ccur, ebuf);
  k_scan_sizes<<<1, 64, 0, stream>>>(ccur, cbase);
  k_bucket_csr<<<NB_C, 256, 0, stream>>>(ebuf, ccur, cbase, offsets, dinv, csr_src);

  k_pack_all<<<496, 256, 0, stream>>>(W1, W2, Wf1, Wf2, Wf3,
                                      pw1h, pw1l, pw2h, pw2l,
                                      p1h, p1l, p2h, p2l, p3h, p3l);

  k_conv<IN_DIM, false><<<(N_NODES + 63) / 64, 512, 0, stream>>>(
      x, nullptr, nullptr, pw1h, pw1l, dinv, bufA);
  k_aggregate<<<4096, 256, 0, stream>>>(bufA, offsets, csr_src, dinv, b1, gh, gl);
  k_conv<HID, true><<<(N_NODES + 63) / 64, 512, 0, stream>>>(
      nullptr, gh, gl, pw2h, pw2l, dinv, bufA);
  k_aggregate<<<4096, 256, 0, stream>>>(bufA, offsets, csr_src, dinv, b2, gh, gl);

  // k_mlp split into two half-grid launches: same work, but halves its per-dispatch
  // duration (~46us) so every other kernel >=47us becomes visible in the top-5 profile.
  k_mlp<<<1562, 512, 0, stream>>>(0,    gh, gl, p1h, p1l, bf1, p2h, p2l, bf2,
                                  p3h, p3l, bf3, out);
  k_mlp<<<1563, 512, 0, stream>>>(1562, gh, gl, p1h, p1l, bf1, p2h, p2l, bf2,
                                  p3h, p3l, bf3, out);
}

// Round 12
// 407.097 us; speedup vs baseline: 1.1718x; 1.1718x over previous
//
#include <hip/hip_runtime.h>

#define N_NODES 100000
#define N_EDGES 1600000
#define IN_DIM  128
#define HID     64
#define MLP_HID 256
#define OUT_DIM 128

#define CB_SHIFT 9
#define CB_SIZE  512
#define NB_C     196   // ceil(100000/512)
#define ECAP     9216  // fixed bucket window capacity (mean 8192 + ~11 sigma)

typedef __attribute__((ext_vector_type(4))) float fx4;
typedef __attribute__((ext_vector_type(8))) short bf16x8;
typedef __attribute__((ext_vector_type(4))) unsigned short u16x4;
typedef __attribute__((ext_vector_type(8))) unsigned short u16x8;
typedef unsigned short u16;
typedef _Float16 f16;

// ---------------- bf16 hi/lo split helpers (HW cvt) ----------------

__device__ __forceinline__ u16 f2b(float x) {
  __bf16 h = (__bf16)x;                     // RNE hardware convert
  return __builtin_bit_cast(u16, h);
}

__device__ __forceinline__ void bsplit(float x, u16& hb, u16& lb) {
  hb = f2b(x);
  float hf = __uint_as_float((unsigned)hb << 16);   // exact reconstruction
  lb = f2b(x - hf);                                  // exact residual, RNE
}

// ---------------- graph build: bucketed counting sort (fixed-capacity windows) -----------

__global__ void k_init_cur(int* __restrict__ ccur) {
  int i = threadIdx.x;
  if (i < NB_C) ccur[i] = i * ECAP;
}

// P1: partition edges into fixed coarse-bucket windows, packed u32 = src<<9 | dst_low9
__global__ __launch_bounds__(256)
void k_partition(const int* __restrict__ src, const int* __restrict__ dst,
                 int* __restrict__ ccur, unsigned* __restrict__ ebuf) {
  __shared__ int h[NB_C];
  __shared__ int bwin[NB_C];
  for (int i = threadIdx.x; i < NB_C; i += 256) h[i] = 0;
  __syncthreads();
  int base = blockIdx.x * 8192;
  int d[32];
  #pragma unroll
  for (int k = 0; k < 32; k++) {
    int i = base + k * 256 + threadIdx.x;
    d[k] = (i < N_EDGES) ? dst[i] : -1;
    if (d[k] >= 0) atomicAdd(&h[d[k] >> CB_SHIFT], 1);
  }
  __syncthreads();
  for (int i = threadIdx.x; i < NB_C; i += 256) {
    int c = h[i];
    bwin[i] = c ? atomicAdd(&ccur[i], c) : 0;
  }
  __syncthreads();
  for (int i = threadIdx.x; i < NB_C; i += 256) h[i] = 0;  // reuse as local cursor
  __syncthreads();
  #pragma unroll
  for (int k = 0; k < 32; k++) {
    if (d[k] >= 0) {
      int i = base + k * 256 + threadIdx.x;
      int b = d[k] >> CB_SHIFT;
      int loc = atomicAdd(&h[b], 1);
      ebuf[bwin[b] + loc] = ((unsigned)src[i] << CB_SHIFT) | (unsigned)(d[k] & (CB_SIZE - 1));
    }
  }
}

// tiny scan of bucket sizes -> csr base per bucket
__global__ void k_scan_sizes(const int* __restrict__ ccur, int* __restrict__ cbase) {
  if (threadIdx.x == 0 && blockIdx.x == 0) {
    int run = 0;
    #pragma unroll 1
    for (int b = 0; b < NB_C; b++) { cbase[b] = run; run += ccur[b] - b * ECAP; }
    cbase[NB_C] = run;
  }
}

// merged: per-bucket hist -> scan -> offsets + dinv -> scatter (LDS cursors)
__global__ __launch_bounds__(256)
void k_bucket_csr(const unsigned* __restrict__ ebuf, const int* __restrict__ ccur,
                  const int* __restrict__ cbase, int* __restrict__ offsets,
                  float* __restrict__ dinv, int* __restrict__ csr_src) {
  __shared__ int h[CB_SIZE];
  __shared__ int ts[256];
  int b = blockIdx.x, t = threadIdx.x;
  for (int i = t; i < CB_SIZE; i += 256) h[i] = 0;
  __syncthreads();
  int e0 = b * ECAP, e1 = ccur[b];
  for (int e = e0 + t; e < e1; e += 256)
    atomicAdd(&h[ebuf[e] & (CB_SIZE - 1)], 1);
  __syncthreads();
  int n0 = b * CB_SIZE;
  int c0 = h[2 * t], c1 = h[2 * t + 1];
  if (n0 + 2 * t     < N_NODES) dinv[n0 + 2 * t]     = rsqrtf((float)(c0 + 1));
  if (n0 + 2 * t + 1 < N_NODES) dinv[n0 + 2 * t + 1] = rsqrtf((float)(c1 + 1));
  int my = c0 + c1;
  ts[t] = my;
  __syncthreads();
  int v = my;
  for (int off = 1; off < 256; off <<= 1) {
    int y = (t >= off) ? ts[t - off] : 0;
    __syncthreads();
    v += y;
    ts[t] = v;
    __syncthreads();
  }
  int excl = cbase[b] + v - my;
  if (n0 + 2 * t     < N_NODES) offsets[n0 + 2 * t]     = excl;
  if (n0 + 2 * t + 1 < N_NODES) offsets[n0 + 2 * t + 1] = excl + c0;
  if (b == NB_C - 1 && t == 0) offsets[N_NODES] = cbase[NB_C];
  // convert h into global cursors
  h[2 * t]     = excl;
  h[2 * t + 1] = excl + c0;
  __syncthreads();
  for (int e = e0 + t; e < e1; e += 256) {
    unsigned p = ebuf[e];
    int pos = atomicAdd(&h[p & (CB_SIZE - 1)], 1);
    csr_src[pos] = (int)(p >> CB_SHIFT);
  }
}

// ---------------- weight pre-pack (all 5 matrices, one kernel) ----------------
// Fragment for (ntile, ks): lane l holds B[k = ks*32 + (l>>4)*8 + j][col = ntile*16 + (l&15)]

__device__ __forceinline__ void pack_one(const float* __restrict__ W, int K, int N, int t,
                                         u16* __restrict__ hi, u16* __restrict__ lo) {
  int k = t / N, n = t % N;
  u16 hb, lb;
  bsplit(W[t], hb, lb);
  int nt = n >> 4, col = n & 15;
  int ks = k >> 5, kr = k & 31;
  int lane = (kr >> 3) * 16 + col;
  int j = kr & 7;
  int ksteps = K >> 5;
  size_t idx = (((size_t)(nt * ksteps + ks)) * 64 + lane) * 8 + j;
  hi[idx] = hb;
  lo[idx] = lb;
}

__global__ __launch_bounds__(256)
void k_pack_all(const float* __restrict__ W1, const float* __restrict__ W2,
                const float* __restrict__ Wf1, const float* __restrict__ Wf2,
                const float* __restrict__ Wf3,
                u16* pw1h, u16* pw1l, u16* pw2h, u16* pw2l,
                u16* p1h, u16* p1l, u16* p2h, u16* p2l, u16* p3h, u16* p3l) {
  int tid = blockIdx.x * 256 + threadIdx.x;
  if (tid < 8192)        pack_one(W1,  IN_DIM,  HID,     tid,          pw1h, pw1l);
  else if (tid < 12288)  pack_one(W2,  HID,     HID,     tid - 8192,   pw2h, pw2l);
  else if (tid < 28672)  pack_one(Wf1, HID,     MLP_HID, tid - 12288,  p1h,  p1l);
  else if (tid < 94208)  pack_one(Wf2, MLP_HID, MLP_HID, tid - 28672,  p2h,  p2l);
  else if (tid < 126976) pack_one(Wf3, MLP_HID, OUT_DIM, tid - 94208,  p3h,  p3l);
}

// ---------------- conv linear via split-bf16 MFMA: out[n] = fp16((X[n] @ W) * dinv[n]) ------
// 512 threads = 8 waves, 64 nodes/block. wave w: m-pair = w>>2, n-tile = w&3.
// fp16 output: halves the aggregate gather traffic (error ~2^-11 rel, within budget).

template<int K, bool SPLIT>
__global__ __launch_bounds__(512, 4)
void k_conv(const float* __restrict__ Xf, const u16* __restrict__ Xh, const u16* __restrict__ Xl,
            const u16* __restrict__ wh, const u16* __restrict__ wl,
            const float* __restrict__ dinv, f16* __restrict__ out) {
  constexpr int STRIDE = K + 8;
  constexpr int KS = K / 32;
  __shared__ u16 s_h[64][STRIDE];
  __shared__ u16 s_l[64][STRIDE];
  const int t = threadIdx.x;
  const int base = blockIdx.x * 64;

  if constexpr (!SPLIT) {
    const int tot4 = 64 * K / 4;
    for (int i = t; i < tot4; i += 512) {
      int f = i * 4;
      int r = f / K, c = f % K;
      int row = base + r;
      if (row >= N_NODES) row = N_NODES - 1;
      float4 v = *(const float4*)(Xf + (size_t)row * K + c);
      u16x4 h4, l4;
      u16 hb, lb;
      bsplit(v.x, hb, lb); h4[0] = hb; l4[0] = lb;
      bsplit(v.y, hb, lb); h4[1] = hb; l4[1] = lb;
      bsplit(v.z, hb, lb); h4[2] = hb; l4[2] = lb;
      bsplit(v.w, hb, lb); h4[3] = hb; l4[3] = lb;
      *(u16x4*)&s_h[r][c] = h4;
      *(u16x4*)&s_l[r][c] = l4;
    }
  } else {
    const int tot8 = 64 * K / 8;
    for (int i = t; i < tot8; i += 512) {
      int r = i / (K / 8), c = (i % (K / 8)) * 8;
      int row = base + r;
      if (row >= N_NODES) row = N_NODES - 1;
      *(u16x8*)&s_h[r][c] = *(const u16x8*)(Xh + (size_t)row * K + c);
      *(u16x8*)&s_l[r][c] = *(const u16x8*)(Xl + (size_t)row * K + c);
    }
  }
  __syncthreads();

  const int w = t >> 6, lane = t & 63;
  const int mg = w >> 2;        // m-pair: m-tiles {2mg, 2mg+1}
  const int nt = w & 3;
  const int lr = lane & 15;
  const int lg = lane >> 4;
  const int kofs = lg * 8;
  const int dr = lg * 4;

  fx4 acc[2];
  #pragma unroll
  for (int m = 0; m < 2; m++) acc[m] = (fx4){0.f, 0.f, 0.f, 0.f};

  #pragma unroll
  for (int ks = 0; ks < KS; ks++) {
    size_t fi = ((size_t)(nt * KS + ks) * 64 + lane) * 8;
    bf16x8 bh = *(const bf16x8*)(wh + fi);
    bf16x8 bl = *(const bf16x8*)(wl + fi);
    #pragma unroll
    for (int m = 0; m < 2; m++) {
      int mrow = (mg * 2 + m) * 16 + lr;
      bf16x8 ah = *(const bf16x8*)&s_h[mrow][ks * 32 + kofs];
      bf16x8 al = *(const bf16x8*)&s_l[mrow][ks * 32 + kofs];
      acc[m] = __builtin_amdgcn_mfma_f32_16x16x32_bf16(al, bh, acc[m], 0, 0, 0);
      acc[m] = __builtin_amdgcn_mfma_f32_16x16x32_bf16(ah, bl, acc[m], 0, 0, 0);
      acc[m] = __builtin_amdgcn_mfma_f32_16x16x32_bf16(ah, bh, acc[m], 0, 0, 0);
    }
  }

  #pragma unroll
  for (int m = 0; m < 2; m++)
    #pragma unroll
    for (int r = 0; r < 4; r++) {
      int row = base + (mg * 2 + m) * 16 + dr + r;
      if (row < N_NODES)
        out[(size_t)row * 64 + nt * 16 + lr] = (f16)(acc[m][r] * dinv[row]);
    }
}

// ---------------- aggregation: fp16 gather, f32 accumulate, pre-split bf16 hi/lo out --------

__global__ __launch_bounds__(256)
void k_aggregate(const f16* __restrict__ h, const int* __restrict__ offsets,
                 const int* __restrict__ csr_src, const float* __restrict__ dinv,
                 const float* __restrict__ bias,
                 u16* __restrict__ oh, u16* __restrict__ ol) {
  int lane = threadIdx.x & 63;
  int wid = (blockIdx.x * 256 + threadIdx.x) >> 6;
  int nw = (gridDim.x * 256) >> 6;
  float bv = bias[lane];
  for (int v = wid; v < N_NODES; v += nw) {
    int e0 = offsets[v], e1 = offsets[v + 1];
    float acc = (float)h[(size_t)v * 64 + lane];   // self-loop (pre-scaled)
    // masked 8-wide gather: 8 loads always in flight, no serial tail
    for (int e = e0; e < e1; e += 8) {
      float a[8];
      #pragma unroll
      for (int k = 0; k < 8; k++) {
        int ee = e + k;
        int cl = ee < e1 ? ee : e0;
        int s = __builtin_amdgcn_readfirstlane(csr_src[cl]);
        float val = (float)h[(size_t)s * 64 + lane];
        a[k] = (ee < e1) ? val : 0.f;
      }
      acc += ((a[0] + a[1]) + (a[2] + a[3])) + ((a[4] + a[5]) + (a[6] + a[7]));
    }
    float r = acc * dinv[v] + bv;
    r = r > 0.f ? r : 0.f;
    u16 hb, lb;
    bsplit(r, hb, lb);
    oh[(size_t)v * 64 + lane] = hb;
    ol[(size_t)v * 64 + lane] = lb;
  }
}

// ---------------- fused MLP via split-bf16 MFMA: 64 -> 256 -> 256 -> 128 ----------------
// R9 known-good form. blk0: node-block offset for the two half-grid launches.

__global__ __launch_bounds__(512, 8)
void k_mlp(int blk0,
           const u16* __restrict__ Xh, const u16* __restrict__ Xl,
           const u16* __restrict__ w1h, const u16* __restrict__ w1l, const float* __restrict__ bb1,
           const u16* __restrict__ w2h, const u16* __restrict__ w2l, const float* __restrict__ bb2,
           const u16* __restrict__ w3h, const u16* __restrict__ w3l, const float* __restrict__ bb3,
           float* __restrict__ out) {
  __shared__ u16 s_h[32][264];
  __shared__ u16 s_l[32][264];
  const int t = threadIdx.x;
  const int w = t >> 6, lane = t & 63;
  const int base = (blk0 + blockIdx.x) * 32;
  const int lr = lane & 15;
  const int lg = lane >> 4;
  const int kofs = lg * 8;
  const int dr = lg * 4;

  fx4 acc[2][2];

  // ---- Layer 1: 64 -> 256 (ksteps=2), A direct from pre-split global ----
  #pragma unroll
  for (int m = 0; m < 2; m++)
    #pragma unroll
    for (int n = 0; n < 2; n++) acc[m][n] = (fx4){0.f, 0.f, 0.f, 0.f};
  #pragma unroll
  for (int ks = 0; ks < 2; ks++) {
    bf16x8 ah[2], al[2];
    #pragma unroll
    for (int m = 0; m < 2; m++) {
      int row = base + m * 16 + lr;
      ah[m] = *(const bf16x8*)(Xh + (size_t)row * 64 + ks * 32 + kofs);
      al[m] = *(const bf16x8*)(Xl + (size_t)row * 64 + ks * 32 + kofs);
    }
    #pragma unroll
    for (int n = 0; n < 2; n++) {
      size_t fi = ((size_t)((w * 2 + n) * 2 + ks) * 64 + lane) * 8;
      bf16x8 bh = *(const bf16x8*)(w1h + fi);
      bf16x8 bl = *(const bf16x8*)(w1l + fi);
      #pragma unroll
      for (int m = 0; m < 2; m++) {
        acc[m][n] = __builtin_amdgcn_mfma_f32_16x16x32_bf16(al[m], bh, acc[m][n], 0, 0, 0);
        acc[m][n] = __builtin_amdgcn_mfma_f32_16x16x32_bf16(ah[m], bl, acc[m][n], 0, 0, 0);
        acc[m][n] = __builtin_amdgcn_mfma_f32_16x16x32_bf16(ah[m], bh, acc[m][n], 0, 0, 0);
      }
    }
  }
  #pragma unroll
  for (int n = 0; n < 2; n++) {
    int nt = w * 2 + n;
    float bias = bb1[nt * 16 + lr];
    #pragma unroll
    for (int m = 0; m < 2; m++)
      #pragma unroll
      for (int r = 0; r < 4; r++) {
        float v = acc[m][n][r] + bias;
        v = v > 0.f ? v : 0.f;
        u16 hb, lb;
        bsplit(v, hb, lb);
        s_h[m * 16 + dr + r][nt * 16 + lr] = hb;
        s_l[m * 16 + dr + r][nt * 16 + lr] = lb;
      }
  }
  __syncthreads();

  // ---- Layer 2: 256 -> 256 (ksteps=8) ----
  #pragma unroll
  for (int m = 0; m < 2; m++)
    #pragma unroll
    for (int n = 0; n < 2; n++) acc[m][n] = (fx4){0.f, 0.f, 0.f, 0.f};
  #pragma unroll
  for (int ks = 0; ks < 8; ks++) {
    bf16x8 ah[2], al[2];
    #pragma unroll
    for (int m = 0; m < 2; m++) {
      ah[m] = *(const bf16x8*)&s_h[m * 16 + lr][ks * 32 + kofs];
      al[m] = *(const bf16x8*)&s_l[m * 16 + lr][ks * 32 + kofs];
    }
    #pragma unroll
    for (int n = 0; n < 2; n++) {
      size_t fi = ((size_t)((w * 2 + n) * 8 + ks) * 64 + lane) * 8;
      bf16x8 bh = *(const bf16x8*)(w2h + fi);
      bf16x8 bl = *(const bf16x8*)(w2l + fi);
      #pragma unroll
      for (int m = 0; m < 2; m++) {
        acc[m][n] = __builtin_amdgcn_mfma_f32_16x16x32_bf16(al[m], bh, acc[m][n], 0, 0, 0);
        acc[m][n] = __builtin_amdgcn_mfma_f32_16x16x32_bf16(ah[m], bl, acc[m][n], 0, 0, 0);
        acc[m][n] = __builtin_amdgcn_mfma_f32_16x16x32_bf16(ah[m], bh, acc[m][n], 0, 0, 0);
      }
    }
  }
  __syncthreads();
  #pragma unroll
  for (int n = 0; n < 2; n++) {
    int nt = w * 2 + n;
    float bias = bb2[nt * 16 + lr];
    #pragma unroll
    for (int m = 0; m < 2; m++)
      #pragma unroll
      for (int r = 0; r < 4; r++) {
        float v = acc[m][n][r] + bias;
        v = v > 0.f ? v : 0.f;
        u16 hb, lb;
        bsplit(v, hb, lb);
        s_h[m * 16 + dr + r][nt * 16 + lr] = hb;
        s_l[m * 16 + dr + r][nt * 16 + lr] = lb;
      }
  }
  __syncthreads();

  // ---- Layer 3: 256 -> 128 (ksteps=8); wave w -> n-tile w ----
  fx4 a3[2];
  #pragma unroll
  for (int m = 0; m < 2; m++) a3[m] = (fx4){0.f, 0.f, 0.f, 0.f};
  #pragma unroll
  for (int ks = 0; ks < 8; ks++) {
    size_t fi = ((size_t)(w * 8 + ks) * 64 + lane) * 8;
    bf16x8 bh = *(const bf16x8*)(w3h + fi);
    bf16x8 bl = *(const bf16x8*)(w3l + fi);
    #pragma unroll
    for (int m = 0; m < 2; m++) {
      bf16x8 ah = *(const bf16x8*)&s_h[m * 16 + lr][ks * 32 + kofs];
      bf16x8 al = *(const bf16x8*)&s_l[m * 16 + lr][ks * 32 + kofs];
      a3[m] = __builtin_amdgcn_mfma_f32_16x16x32_bf16(al, bh, a3[m], 0, 0, 0);
      a3[m] = __builtin_amdgcn_mfma_f32_16x16x32_bf16(ah, bl, a3[m], 0, 0, 0);
      a3[m] = __builtin_amdgcn_mfma_f32_16x16x32_bf16(ah, bh, a3[m], 0, 0, 0);
    }
  }
  {
    int col = w * 16 + lr;
    float bias = bb3[col];
    #pragma unroll
    for (int m = 0; m < 2; m++)
      #pragma unroll
      for (int r = 0; r < 4; r++) {
        int row = base + m * 16 + dr + r;
        float v = a3[m][r] + bias;
        out[(size_t)row * 128 + col] = v > 0.f ? v : 0.f;
      }
  }
}

// ---------------- launch ----------------

extern "C" void kernel_launch(void* const* d_in, const int* in_sizes, int n_in,
                              void* d_out, int out_size, void* d_ws, size_t ws_size,
                              hipStream_t stream) {
  const float* x   = (const float*)d_in[0];
  const int*   ei  = (const int*)d_in[1];
  const float* W1  = (const float*)d_in[2];
  const float* b1  = (const float*)d_in[3];
  const float* W2  = (const float*)d_in[4];
  const float* b2  = (const float*)d_in[5];
  const float* Wf1 = (const float*)d_in[6];
  const float* bf1 = (const float*)d_in[7];
  const float* Wf2 = (const float*)d_in[8];
  const float* bf2 = (const float*)d_in[9];
  const float* Wf3 = (const float*)d_in[10];
  const float* bf3 = (const float*)d_in[11];
  float* out = (float*)d_out;

  const int* src = ei;             // edge_index[0]
  const int* dst = ei + N_EDGES;   // edge_index[1]

  // workspace layout (16B-aligned chunks)
  int*      ccur    = (int*)d_ws;           // 256
  int*      cbase   = ccur + 256;           // 256 (NB_C+1 used)
  int*      offsets = cbase + 256;          // 100352+16
  int*      csr_src = offsets + 100368;     // E
  float*    dinv    = (float*)(csr_src + N_EDGES);
  f16*      bufA16  = (f16*)(dinv + 100352);         // fp16 conv output, N*64 (12.8MB)
  u16*      gh      = (u16*)(bufA16 + 6400256);      // pre-split aggregate out (hi)
  u16*      gl      = gh + 6400256;                  // (lo)
  u16*      p1h     = gl + 6400256;
  u16*      p1l     = p1h + HID * MLP_HID;
  u16*      p2h     = p1l + HID * MLP_HID;
  u16*      p2l     = p2h + MLP_HID * MLP_HID;
  u16*      p3h     = p2l + MLP_HID * MLP_HID;
  u16*      p3l     = p3h + MLP_HID * OUT_DIM;
  u16*      pw1h    = p3l + MLP_HID * OUT_DIM;
  u16*      pw1l    = pw1h + IN_DIM * HID;
  u16*      pw2h    = pw1l + IN_DIM * HID;
  u16*      pw2l    = pw2h + HID * HID;
  unsigned* ebuf    = (unsigned*)bufA16;    // aliased (7.2MB of 12.8MB): dead before conv1

  k_init_cur  <<<1, 256, 0, stream>>>(ccur);
  k_partition <<<196, 256, 0, stream>>>(src, dst, ccur, ebuf);
  k_scan_sizes<<<1, 64, 0, stream>>>(ccur, cbase);
  k_bucket_csr<<<NB_C, 256, 0, stream>>>(ebuf, ccur, cbase, offsets, dinv, csr_src);

  k_pack_all<<<496, 256, 0, stream>>>(W1, W2, Wf1, Wf2, Wf3,
                                      pw1h, pw1l, pw2h, pw2l,
                                      p1h, p1l, p2h, p2l, p3h, p3l);

  k_conv<IN_DIM, false><<<(N_NODES + 63) / 64, 512, 0, stream>>>(
      x, nullptr, nullptr, pw1h, pw1l, dinv, bufA16);
  k_aggregate<<<4096, 256, 0, stream>>>(bufA16, offsets, csr_src, dinv, b1, gh, gl);
  k_conv<HID, true><<<(N_NODES + 63) / 64, 512, 0, stream>>>(
      nullptr, gh, gl, pw2h, pw2l, dinv, bufA16);
  k_aggregate<<<4096, 256, 0, stream>>>(bufA16, offsets, csr_src, dinv, b2, gh, gl);

  // k_mlp split into two half-grid launches (profiling visibility)
  k_mlp<<<1562, 512, 0, stream>>>(0,    gh, gl, p1h, p1l, bf1, p2h, p2l, bf2,
                                  p3h, p3l, bf3, out);
  k_mlp<<<1563, 512, 0, stream>>>(1562, gh, gl, p1h, p1l, bf1, p2h, p2l, bf2,
                                  p3h, p3l, bf3, out);
}

// Round 14
// 394.357 us; speedup vs baseline: 1.2097x; 1.0323x over previous
//
#include <hip/hip_runtime.h>

#define N_NODES 100000
#define N_EDGES 1600000
#define IN_DIM  128
#define HID     64
#define MLP_HID 256
#define OUT_DIM 128

#define CB_SHIFT 9
#define CB_SIZE  512
#define NB_C     196   // ceil(100000/512)
#define ECAP     9216  // fixed bucket window capacity (mean 8192 + ~11 sigma)

typedef __attribute__((ext_vector_type(4))) float fx4;
typedef __attribute__((ext_vector_type(8))) short bf16x8;
typedef __attribute__((ext_vector_type(4))) unsigned short u16x4;
typedef __attribute__((ext_vector_type(8))) unsigned short u16x8;
typedef unsigned short u16;
typedef _Float16 f16;

// ---------------- bf16 hi/lo split helpers (HW cvt) ----------------

__device__ __forceinline__ u16 f2b(float x) {
  __bf16 h = (__bf16)x;                     // RNE hardware convert
  return __builtin_bit_cast(u16, h);
}

__device__ __forceinline__ void bsplit(float x, u16& hb, u16& lb) {
  hb = f2b(x);
  float hf = __uint_as_float((unsigned)hb << 16);   // exact reconstruction
  lb = f2b(x - hf);                                  // exact residual, RNE
}

// ---------------- graph build: bucketed counting sort (fixed-capacity windows) -----------

__global__ void k_init_cur(int* __restrict__ ccur) {
  int i = threadIdx.x;
  if (i < NB_C) ccur[i] = i * ECAP;
}

// P1: partition edges into fixed coarse-bucket windows, packed u32 = src<<9 | dst_low9
__global__ __launch_bounds__(256)
void k_partition(const int* __restrict__ src, const int* __restrict__ dst,
                 int* __restrict__ ccur, unsigned* __restrict__ ebuf) {
  __shared__ int h[NB_C];
  __shared__ int bwin[NB_C];
  for (int i = threadIdx.x; i < NB_C; i += 256) h[i] = 0;
  __syncthreads();
  int base = blockIdx.x * 8192;
  int d[32];
  #pragma unroll
  for (int k = 0; k < 32; k++) {
    int i = base + k * 256 + threadIdx.x;
    d[k] = (i < N_EDGES) ? dst[i] : -1;
    if (d[k] >= 0) atomicAdd(&h[d[k] >> CB_SHIFT], 1);
  }
  __syncthreads();
  for (int i = threadIdx.x; i < NB_C; i += 256) {
    int c = h[i];
    bwin[i] = c ? atomicAdd(&ccur[i], c) : 0;
  }
  __syncthreads();
  for (int i = threadIdx.x; i < NB_C; i += 256) h[i] = 0;  // reuse as local cursor
  __syncthreads();
  #pragma unroll
  for (int k = 0; k < 32; k++) {
    if (d[k] >= 0) {
      int i = base + k * 256 + threadIdx.x;
      int b = d[k] >> CB_SHIFT;
      int loc = atomicAdd(&h[b], 1);
      ebuf[bwin[b] + loc] = ((unsigned)src[i] << CB_SHIFT) | (unsigned)(d[k] & (CB_SIZE - 1));
    }
  }
}

// tiny scan of bucket sizes -> csr base per bucket
__global__ void k_scan_sizes(const int* __restrict__ ccur, int* __restrict__ cbase) {
  if (threadIdx.x == 0 && blockIdx.x == 0) {
    int run = 0;
    #pragma unroll 1
    for (int b = 0; b < NB_C; b++) { cbase[b] = run; run += ccur[b] - b * ECAP; }
    cbase[NB_C] = run;
  }
}

// merged: per-bucket hist -> scan -> offsets + dinv -> scatter (LDS cursors)
__global__ __launch_bounds__(256)
void k_bucket_csr(const unsigned* __restrict__ ebuf, const int* __restrict__ ccur,
                  const int* __restrict__ cbase, int* __restrict__ offsets,
                  float* __restrict__ dinv, int* __restrict__ csr_src) {
  __shared__ int h[CB_SIZE];
  __shared__ int ts[256];
  int b = blockIdx.x, t = threadIdx.x;
  for (int i = t; i < CB_SIZE; i += 256) h[i] = 0;
  __syncthreads();
  int e0 = b * ECAP, e1 = ccur[b];
  for (int e = e0 + t; e < e1; e += 256)
    atomicAdd(&h[ebuf[e] & (CB_SIZE - 1)], 1);
  __syncthreads();
  int n0 = b * CB_SIZE;
  int c0 = h[2 * t], c1 = h[2 * t + 1];
  if (n0 + 2 * t     < N_NODES) dinv[n0 + 2 * t]     = rsqrtf((float)(c0 + 1));
  if (n0 + 2 * t + 1 < N_NODES) dinv[n0 + 2 * t + 1] = rsqrtf((float)(c1 + 1));
  int my = c0 + c1;
  ts[t] = my;
  __syncthreads();
  int v = my;
  for (int off = 1; off < 256; off <<= 1) {
    int y = (t >= off) ? ts[t - off] : 0;
    __syncthreads();
    v += y;
    ts[t] = v;
    __syncthreads();
  }
  int excl = cbase[b] + v - my;
  if (n0 + 2 * t     < N_NODES) offsets[n0 + 2 * t]     = excl;
  if (n0 + 2 * t + 1 < N_NODES) offsets[n0 + 2 * t + 1] = excl + c0;
  if (b == NB_C - 1 && t == 0) offsets[N_NODES] = cbase[NB_C];
  // convert h into global cursors
  h[2 * t]     = excl;
  h[2 * t + 1] = excl + c0;
  __syncthreads();
  for (int e = e0 + t; e < e1; e += 256) {
    unsigned p = ebuf[e];
    int pos = atomicAdd(&h[p & (CB_SIZE - 1)], 1);
    csr_src[pos] = (int)(p >> CB_SHIFT);
  }
}

// ---------------- weight pre-pack (all 5 matrices, one kernel) ----------------
// Fragment for (ntile, ks): lane l holds B[k = ks*32 + (l>>4)*8 + j][col = ntile*16 + (l&15)]

__device__ __forceinline__ void pack_one(const float* __restrict__ W, int K, int N, int t,
                                         u16* __restrict__ hi, u16* __restrict__ lo) {
  int k = t / N, n = t % N;
  u16 hb, lb;
  bsplit(W[t], hb, lb);
  int nt = n >> 4, col = n & 15;
  int ks = k >> 5, kr = k & 31;
  int lane = (kr >> 3) * 16 + col;
  int j = kr & 7;
  int ksteps = K >> 5;
  size_t idx = (((size_t)(nt * ksteps + ks)) * 64 + lane) * 8 + j;
  hi[idx] = hb;
  lo[idx] = lb;
}

__global__ __launch_bounds__(256)
void k_pack_all(const float* __restrict__ W1, const float* __restrict__ W2,
                const float* __restrict__ Wf1, const float* __restrict__ Wf2,
                const float* __restrict__ Wf3,
                u16* pw1h, u16* pw1l, u16* pw2h, u16* pw2l,
                u16* p1h, u16* p1l, u16* p2h, u16* p2l, u16* p3h, u16* p3l) {
  int tid = blockIdx.x * 256 + threadIdx.x;
  if (tid < 8192)        pack_one(W1,  IN_DIM,  HID,     tid,          pw1h, pw1l);
  else if (tid < 12288)  pack_one(W2,  HID,     HID,     tid - 8192,   pw2h, pw2l);
  else if (tid < 28672)  pack_one(Wf1, HID,     MLP_HID, tid - 12288,  p1h,  p1l);
  else if (tid < 94208)  pack_one(Wf2, MLP_HID, MLP_HID, tid - 28672,  p2h,  p2l);
  else if (tid < 126976) pack_one(Wf3, MLP_HID, OUT_DIM, tid - 94208,  p3h,  p3l);
}

// ---------------- conv linear via split-bf16 MFMA: out[n] = fp16((X[n] @ W) * dinv[n]) ------
// 512 threads = 8 waves, 64 nodes/block. wave w: m-pair = w>>2, n-tile = w&3.

template<int K, bool SPLIT>
__global__ __launch_bounds__(512, 4)
void k_conv(const float* __restrict__ Xf, const u16* __restrict__ Xh, const u16* __restrict__ Xl,
            const u16* __restrict__ wh, const u16* __restrict__ wl,
            const float* __restrict__ dinv, f16* __restrict__ out) {
  constexpr int STRIDE = K + 8;
  constexpr int KS = K / 32;
  __shared__ u16 s_h[64][STRIDE];
  __shared__ u16 s_l[64][STRIDE];
  const int t = threadIdx.x;
  const int base = blockIdx.x * 64;

  if constexpr (!SPLIT) {
    const int tot4 = 64 * K / 4;
    for (int i = t; i < tot4; i += 512) {
      int f = i * 4;
      int r = f / K, c = f % K;
      int row = base + r;
      if (row >= N_NODES) row = N_NODES - 1;
      float4 v = *(const float4*)(Xf + (size_t)row * K + c);
      u16x4 h4, l4;
      u16 hb, lb;
      bsplit(v.x, hb, lb); h4[0] = hb; l4[0] = lb;
      bsplit(v.y, hb, lb); h4[1] = hb; l4[1] = lb;
      bsplit(v.z, hb, lb); h4[2] = hb; l4[2] = lb;
      bsplit(v.w, hb, lb); h4[3] = hb; l4[3] = lb;
      *(u16x4*)&s_h[r][c] = h4;
      *(u16x4*)&s_l[r][c] = l4;
    }
  } else {
    const int tot8 = 64 * K / 8;
    for (int i = t; i < tot8; i += 512) {
      int r = i / (K / 8), c = (i % (K / 8)) * 8;
      int row = base + r;
      if (row >= N_NODES) row = N_NODES - 1;
      *(u16x8*)&s_h[r][c] = *(const u16x8*)(Xh + (size_t)row * K + c);
      *(u16x8*)&s_l[r][c] = *(const u16x8*)(Xl + (size_t)row * K + c);
    }
  }
  __syncthreads();

  const int w = t >> 6, lane = t & 63;
  const int mg = w >> 2;        // m-pair: m-tiles {2mg, 2mg+1}
  const int nt = w & 3;
  const int lr = lane & 15;
  const int lg = lane >> 4;
  const int kofs = lg * 8;
  const int dr = lg * 4;

  fx4 acc[2];
  #pragma unroll
  for (int m = 0; m < 2; m++) acc[m] = (fx4){0.f, 0.f, 0.f, 0.f};

  #pragma unroll
  for (int ks = 0; ks < KS; ks++) {
    size_t fi = ((size_t)(nt * KS + ks) * 64 + lane) * 8;
    bf16x8 bh = *(const bf16x8*)(wh + fi);
    bf16x8 bl = *(const bf16x8*)(wl + fi);
    #pragma unroll
    for (int m = 0; m < 2; m++) {
      int mrow = (mg * 2 + m) * 16 + lr;
      bf16x8 ah = *(const bf16x8*)&s_h[mrow][ks * 32 + kofs];
      bf16x8 al = *(const bf16x8*)&s_l[mrow][ks * 32 + kofs];
      acc[m] = __builtin_amdgcn_mfma_f32_16x16x32_bf16(al, bh, acc[m], 0, 0, 0);
      acc[m] = __builtin_amdgcn_mfma_f32_16x16x32_bf16(ah, bl, acc[m], 0, 0, 0);
      acc[m] = __builtin_amdgcn_mfma_f32_16x16x32_bf16(ah, bh, acc[m], 0, 0, 0);
    }
  }

  #pragma unroll
  for (int m = 0; m < 2; m++)
    #pragma unroll
    for (int r = 0; r < 4; r++) {
      int row = base + (mg * 2 + m) * 16 + dr + r;
      if (row < N_NODES)
        out[(size_t)row * 64 + nt * 16 + lr] = (f16)(acc[m][r] * dinv[row]);
    }
}

// ---------------- aggregation: fp16 gather, scalar edge list, f32 accumulate ----------------
// e0/e1 forced to SGPR -> csr_src[e+k] are s_loads (scalar pipe); h-gather is the only
// vector-memory stream. 32-bit element indexing; unmasked full blocks + one masked tail.

__global__ __launch_bounds__(256)
void k_aggregate(const f16* __restrict__ h, const int* __restrict__ offsets,
                 const int* __restrict__ csr_src, const float* __restrict__ dinv,
                 const float* __restrict__ bias,
                 u16* __restrict__ oh, u16* __restrict__ ol) {
  int lane = threadIdx.x & 63;
  int wid = (blockIdx.x * 256 + threadIdx.x) >> 6;
  int nw = (gridDim.x * 256) >> 6;
  float bv = bias[lane];
  const f16* hl = h + lane;   // per-lane base; per-edge offset = s*64 elements (32-bit)
  for (int v = wid; v < N_NODES; v += nw) {
    int e0 = __builtin_amdgcn_readfirstlane(offsets[v]);
    int e1 = __builtin_amdgcn_readfirstlane(offsets[v + 1]);
    float acc = (float)hl[(unsigned)v * 64u];   // self-loop (pre-scaled)
    int efull = e0 + ((e1 - e0) & ~7);
    int e = e0;
    for (; e < efull; e += 8) {
      float a0 = (float)hl[(unsigned)csr_src[e + 0] * 64u];
      float a1 = (float)hl[(unsigned)csr_src[e + 1] * 64u];
      float a2 = (float)hl[(unsigned)csr_src[e + 2] * 64u];
      float a3 = (float)hl[(unsigned)csr_src[e + 3] * 64u];
      float a4 = (float)hl[(unsigned)csr_src[e + 4] * 64u];
      float a5 = (float)hl[(unsigned)csr_src[e + 5] * 64u];
      float a6 = (float)hl[(unsigned)csr_src[e + 6] * 64u];
      float a7 = (float)hl[(unsigned)csr_src[e + 7] * 64u];
      acc += ((a0 + a1) + (a2 + a3)) + ((a4 + a5) + (a6 + a7));
    }
    if (e < e1) {   // single masked tail block (<=7 edges)
      float a[8];
      #pragma unroll
      for (int k = 0; k < 8; k++) {
        int ee = e + k;
        int cl = ee < e1 ? ee : e0;
        float val = (float)hl[(unsigned)csr_src[cl] * 64u];
        a[k] = (ee < e1) ? val : 0.f;
      }
      acc += ((a[0] + a[1]) + (a[2] + a[3])) + ((a[4] + a[5]) + (a[6] + a[7]));
    }
    float r = acc * dinv[v] + bv;
    r = r > 0.f ? r : 0.f;
    u16 hb, lb;
    bsplit(r, hb, lb);
    oh[(size_t)v * 64 + lane] = hb;
    ol[(size_t)v * 64 + lane] = lb;
  }
}

// ---------------- fused MLP via split-bf16 MFMA: 64 -> 256 -> 256 -> 128 ----------------
// R9 known-good form. blk0: node-block offset for the two half-grid launches.

__global__ __launch_bounds__(512, 8)
void k_mlp(int blk0,
           const u16* __restrict__ Xh, const u16* __restrict__ Xl,
           const u16* __restrict__ w1h, const u16* __restrict__ w1l, const float* __restrict__ bb1,
           const u16* __restrict__ w2h, const u16* __restrict__ w2l, const float* __restrict__ bb2,
           const u16* __restrict__ w3h, const u16* __restrict__ w3l, const float* __restrict__ bb3,
           float* __restrict__ out) {
  __shared__ u16 s_h[32][264];
  __shared__ u16 s_l[32][264];
  const int t = threadIdx.x;
  const int w = t >> 6, lane = t & 63;
  const int base = (blk0 + blockIdx.x) * 32;
  const int lr = lane & 15;
  const int lg = lane >> 4;
  const int kofs = lg * 8;
  const int dr = lg * 4;

  fx4 acc[2][2];

  // ---- Layer 1: 64 -> 256 (ksteps=2), A direct from pre-split global ----
  #pragma unroll
  for (int m = 0; m < 2; m++)
    #pragma unroll
    for (int n = 0; n < 2; n++) acc[m][n] = (fx4){0.f, 0.f, 0.f, 0.f};
  #pragma unroll
  for (int ks = 0; ks < 2; ks++) {
    bf16x8 ah[2], al[2];
    #pragma unroll
    for (int m = 0; m < 2; m++) {
      int row = base + m * 16 + lr;
      ah[m] = *(const bf16x8*)(Xh + (size_t)row * 64 + ks * 32 + kofs);
      al[m] = *(const bf16x8*)(Xl + (size_t)row * 64 + ks * 32 + kofs);
    }
    #pragma unroll
    for (int n = 0; n < 2; n++) {
      size_t fi = ((size_t)((w * 2 + n) * 2 + ks) * 64 + lane) * 8;
      bf16x8 bh = *(const bf16x8*)(w1h + fi);
      bf16x8 bl = *(const bf16x8*)(w1l + fi);
      #pragma unroll
      for (int m = 0; m < 2; m++) {
        acc[m][n] = __builtin_amdgcn_mfma_f32_16x16x32_bf16(al[m], bh, acc[m][n], 0, 0, 0);
        acc[m][n] = __builtin_amdgcn_mfma_f32_16x16x32_bf16(ah[m], bl, acc[m][n], 0, 0, 0);
        acc[m][n] = __builtin_amdgcn_mfma_f32_16x16x32_bf16(ah[m], bh, acc[m][n], 0, 0, 0);
      }
    }
  }
  #pragma unroll
  for (int n = 0; n < 2; n++) {
    int nt = w * 2 + n;
    float bias = bb1[nt * 16 + lr];
    #pragma unroll
    for (int m = 0; m < 2; m++)
      #pragma unroll
      for (int r = 0; r < 4; r++) {
        float v = acc[m][n][r] + bias;
        v = v > 0.f ? v : 0.f;
        u16 hb, lb;
        bsplit(v, hb, lb);
        s_h[m * 16 + dr + r][nt * 16 + lr] = hb;
        s_l[m * 16 + dr + r][nt * 16 + lr] = lb;
      }
  }
  __syncthreads();

  // ---- Layer 2: 256 -> 256 (ksteps=8) ----
  #pragma unroll
  for (int m = 0; m < 2; m++)
    #pragma unroll
    for (int n = 0; n < 2; n++) acc[m][n] = (fx4){0.f, 0.f, 0.f, 0.f};
  #pragma unroll
  for (int ks = 0; ks < 8; ks++) {
    bf16x8 ah[2], al[2];
    #pragma unroll
    for (int m = 0; m < 2; m++) {
      ah[m] = *(const bf16x8*)&s_h[m * 16 + lr][ks * 32 + kofs];
      al[m] = *(const bf16x8*)&s_l[m * 16 + lr][ks * 32 + kofs];
    }
    #pragma unroll
    for (int n = 0; n < 2; n++) {
      size_t fi = ((size_t)((w * 2 + n) * 8 + ks) * 64 + lane) * 8;
      bf16x8 bh = *(const bf16x8*)(w2h + fi);
      bf16x8 bl = *(const bf16x8*)(w2l + fi);
      #pragma unroll
      for (int m = 0; m < 2; m++) {
        acc[m][n] = __builtin_amdgcn_mfma_f32_16x16x32_bf16(al[m], bh, acc[m][n], 0, 0, 0);
        acc[m][n] = __builtin_amdgcn_mfma_f32_16x16x32_bf16(ah[m], bl, acc[m][n], 0, 0, 0);
        acc[m][n] = __builtin_amdgcn_mfma_f32_16x16x32_bf16(ah[m], bh, acc[m][n], 0, 0, 0);
      }
    }
  }
  __syncthreads();
  #pragma unroll
  for (int n = 0; n < 2; n++) {
    int nt = w * 2 + n;
    float bias = bb2[nt * 16 + lr];
    #pragma unroll
    for (int m = 0; m < 2; m++)
      #pragma unroll
      for (int r = 0; r < 4; r++) {
        float v = acc[m][n][r] + bias;
        v = v > 0.f ? v : 0.f;
        u16 hb, lb;
        bsplit(v, hb, lb);
        s_h[m * 16 + dr + r][nt * 16 + lr] = hb;
        s_l[m * 16 + dr + r][nt * 16 + lr] = lb;
      }
  }
  __syncthreads();

  // ---- Layer 3: 256 -> 128 (ksteps=8); wave w -> n-tile w ----
  fx4 a3[2];
  #pragma unroll
  for (int m = 0; m < 2; m++) a3[m] = (fx4){0.f, 0.f, 0.f, 0.f};
  #pragma unroll
  for (int ks = 0; ks < 8; ks++) {
    size_t fi = ((size_t)(w * 8 + ks) * 64 + lane) * 8;
    bf16x8 bh = *(const bf16x8*)(w3h + fi);
    bf16x8 bl = *(const bf16x8*)(w3l + fi);
    #pragma unroll
    for (int m = 0; m < 2; m++) {
      bf16x8 ah = *(const bf16x8*)&s_h[m * 16 + lr][ks * 32 + kofs];
      bf16x8 al = *(const bf16x8*)&s_l[m * 16 + lr][ks * 32 + kofs];
      a3[m] = __builtin_amdgcn_mfma_f32_16x16x32_bf16(al, bh, a3[m], 0, 0, 0);
      a3[m] = __builtin_amdgcn_mfma_f32_16x16x32_bf16(ah, bl, a3[m], 0, 0, 0);
      a3[m] = __builtin_amdgcn_mfma_f32_16x16x32_bf16(ah, bh, a3[m], 0, 0, 0);
    }
  }
  {
    int col = w * 16 + lr;
    float bias = bb3[col];
    #pragma unroll
    for (int m = 0; m < 2; m++)
      #pragma unroll
      for (int r = 0; r < 4; r++) {
        int row = base + m * 16 + dr + r;
        float v = a3[m][r] + bias;
        out[(size_t)row * 128 + col] = v > 0.f ? v : 0.f;
      }
  }
}

// ---------------- launch ----------------

extern "C" void kernel_launch(void* const* d_in, const int* in_sizes, int n_in,
                              void* d_out, int out_size, void* d_ws, size_t ws_size,
                              hipStream_t stream) {
  const float* x   = (const float*)d_in[0];
  const int*   ei  = (const int*)d_in[1];
  const float* W1  = (const float*)d_in[2];
  const float* b1  = (const float*)d_in[3];
  const float* W2  = (const float*)d_in[4];
  const float* b2  = (const float*)d_in[5];
  const float* Wf1 = (const float*)d_in[6];
  const float* bf1 = (const float*)d_in[7];
  const float* Wf2 = (const float*)d_in[8];
  const float* bf2 = (const float*)d_in[9];
  const float* Wf3 = (const float*)d_in[10];
  const float* bf3 = (const float*)d_in[11];
  float* out = (float*)d_out;

  const int* src = ei;             // edge_index[0]
  const int* dst = ei + N_EDGES;   // edge_index[1]

  // workspace layout (16B-aligned chunks)
  int*      ccur    = (int*)d_ws;           // 256
  int*      cbase   = ccur + 256;           // 256 (NB_C+1 used)
  int*      offsets = cbase + 256;          // 100352+16
  int*      csr_src = offsets + 100368;     // E
  float*    dinv    = (float*)(csr_src + N_EDGES);
  f16*      bufA16  = (f16*)(dinv + 100352);         // fp16 conv output, N*64 (12.8MB)
  u16*      gh      = (u16*)(bufA16 + 6400256);      // pre-split aggregate out (hi)
  u16*      gl      = gh + 6400256;                  // (lo)
  u16*      p1h     = gl + 6400256;
  u16*      p1l     = p1h + HID * MLP_HID;
  u16*      p2h     = p1l + HID * MLP_HID;
  u16*      p2l     = p2h + MLP_HID * MLP_HID;
  u16*      p3h     = p2l + MLP_HID * MLP_HID;
  u16*      p3l     = p3h + MLP_HID * OUT_DIM;
  u16*      pw1h    = p3l + MLP_HID * OUT_DIM;
  u16*      pw1l    = pw1h + IN_DIM * HID;
  u16*      pw2h    = pw1l + IN_DIM * HID;
  u16*      pw2l    = pw2h + HID * HID;
  unsigned* ebuf    = (unsigned*)bufA16;    // aliased (7.2MB of 12.8MB): dead before conv1

  k_init_cur  <<<1, 256, 0, stream>>>(ccur);
  k_partition <<<196, 256, 0, stream>>>(src, dst, ccur, ebuf);
  k_scan_sizes<<<1, 64, 0, stream>>>(ccur, cbase);
  k_bucket_csr<<<NB_C, 256, 0, stream>>>(ebuf, ccur, cbase, offsets, dinv, csr_src);

  k_pack_all<<<496, 256, 0, stream>>>(W1, W2, Wf1, Wf2, Wf3,
                                      pw1h, pw1l, pw2h, pw2l,
                                      p1h, p1l, p2h, p2l, p3h, p3l);

  k_conv<IN_DIM, false><<<(N_NODES + 63) / 64, 512, 0, stream>>>(
      x, nullptr, nullptr, pw1h, pw1l, dinv, bufA16);
  k_aggregate<<<4096, 256, 0, stream>>>(bufA16, offsets, csr_src, dinv, b1, gh, gl);
  k_conv<HID, true><<<(N_NODES + 63) / 64, 512, 0, stream>>>(
      nullptr, gh, gl, pw2h, pw2l, dinv, bufA16);
  k_aggregate<<<4096, 256, 0, stream>>>(bufA16, offsets, csr_src, dinv, b2, gh, gl);

  // k_mlp split into two half-grid launches (profiling visibility)
  k_mlp<<<1562, 512, 0, stream>>>(0,    gh, gl, p1h, p1l, bf1, p2h, p2l, bf2,
                                  p3h, p3l, bf3, out);
  k_mlp<<<1563, 512, 0, stream>>>(1562, gh, gl, p1h, p1l, bf1, p2h, p2l, bf2,
                                  p3h, p3l, bf3, out);
}